// Round 3
// baseline (201.238 us; speedup 1.0000x reference)
//
#include <hip/hip_runtime.h>
#include <hip/hip_bf16.h>

// Problem: B=64, S=512, D=512.
// out[b] = (sum_{valid i} max_{valid j} sim[i,j] + sum_{valid j} max_{valid i} sim[i,j]) / (n1+n2)
// sim = normalize(e1) @ normalize(e2)^T per batch.
//
// Fast path (needs ~65 MB ws):
//   prep_kernel : L2-normalize rows, write bf16 n1/n2 -> ws. 4 rows/wave for ILP
//                 (1 row/wave was latency-bound at 2.6 TB/s).
//   sim_kernel  : bf16 MFMA 128x256/block, global_load_lds x16B staging,
//                 XOR-swizzled LDS, masked row/col max partials -> ws
//   final_kernel: per-batch reduction -> out
// Fallback path (small ws): round-1 proven kernels.

typedef __attribute__((ext_vector_type(8))) short bf16x8;   // 8 bf16 in 4 VGPRs
typedef __attribute__((ext_vector_type(4))) float f32x4;

#define NEGBIG (-1e9f)
#define CAST_LDS(p) ((__attribute__((address_space(3))) void*)(p))
#define CAST_G(p)   ((const __attribute__((address_space(1))) void*)(p))

__device__ __forceinline__ unsigned bfbits(float f) {
    union { float f; unsigned u; } c; c.f = f;
    // round-to-nearest-even bf16 (inputs finite)
    return (c.u + 0x7fffu + ((c.u >> 16) & 1u)) >> 16;
}
__device__ __forceinline__ unsigned packbf(float lo, float hi) {
    return (bfbits(hi) << 16) | bfbits(lo);
}

// ---------------- fast path kernel 1: normalize -> bf16 ----------------
// 4 rows per wave: all loads issued up front, 4 independent reduce chains
// interleave across the 6 shuffle levels (latency hiding), 4 packed stores.
// Grid: 4096 blocks x 4 waves x 4 rows = 65536 rows (0..32767 e1, rest e2).
__global__ __launch_bounds__(256)
void prep_kernel(const float* __restrict__ e1, const float* __restrict__ e2,
                 ushort* __restrict__ n1, ushort* __restrict__ n2)
{
    const int lane = threadIdx.x & 63;
    const int w    = threadIdx.x >> 6;
    const int gw   = blockIdx.x * 4 + w;          // 0..16383
    const int row0 = gw * 4;                      // first of 4 rows
    const bool is1 = row0 < 32768;
    const float* src = is1 ? (e1 + (size_t)row0 * 512)
                           : (e2 + (size_t)(row0 - 32768) * 512);
    ushort* dst = is1 ? (n1 + (size_t)row0 * 512)
                      : (n2 + (size_t)(row0 - 32768) * 512);

    float4 a[4], c[4];
    #pragma unroll
    for (int r = 0; r < 4; ++r) {
        const float4* s4 = reinterpret_cast<const float4*>(src + r * 512);
        a[r] = s4[lane * 2];
        c[r] = s4[lane * 2 + 1];
    }
    float ss[4];
    #pragma unroll
    for (int r = 0; r < 4; ++r)
        ss[r] = a[r].x*a[r].x + a[r].y*a[r].y + a[r].z*a[r].z + a[r].w*a[r].w
              + c[r].x*c[r].x + c[r].y*c[r].y + c[r].z*c[r].z + c[r].w*c[r].w;
    #pragma unroll
    for (int m = 32; m; m >>= 1) {
        #pragma unroll
        for (int r = 0; r < 4; ++r) ss[r] += __shfl_xor(ss[r], m);
    }
    #pragma unroll
    for (int r = 0; r < 4; ++r) {
        float iv = 1.0f / fmaxf(sqrtf(ss[r]), 1e-8f);
        uint4 p;
        p.x = packbf(a[r].x * iv, a[r].y * iv);
        p.y = packbf(a[r].z * iv, a[r].w * iv);
        p.z = packbf(c[r].x * iv, c[r].y * iv);
        p.w = packbf(c[r].z * iv, c[r].w * iv);
        reinterpret_cast<uint4*>(dst + r * 512)[lane] = p;
    }
}

// ---------------- fast path kernel 2: masked sim max partials ----------------
// grid: (rt=0..3, ct=0..1, b=0..63). 256 thr = 4 waves (2x2 of 64x64).
// Tiles: 128 rows x 32 bf16 (64B/row), NO pad (global_load_lds constraint).
// Swizzle: LDS[row][slot] = G[row][slot ^ s(row)], s(r) = (r ^ (r>>2)) & 3
// -> fragment b128 reads land <=2-way on banks.
__global__ __launch_bounds__(256, 2)
void sim_kernel(const ushort* __restrict__ n1, const ushort* __restrict__ n2,
                const int* __restrict__ m1g, const int* __restrict__ m2g,
                float* __restrict__ rowmax_p,   // [B][2][512]
                float* __restrict__ colmax_p)   // [B][4][512]
{
    const int rt  = blockIdx.x;
    const int ct  = blockIdx.y;
    const int b   = blockIdx.z;
    const int tid = threadIdx.x;
    const int lane = tid & 63;
    const int w    = tid >> 6;
    const int wm   = w >> 1;
    const int wn   = w & 1;
    const int q    = lane >> 4;
    const int ln   = lane & 15;

    __shared__ __align__(16) ushort sA[128 * 32];   // 8 KB
    __shared__ __align__(16) ushort sB[128 * 32];   // 8 KB
    __shared__ float spr[2][128];
    __shared__ float spc[2][128];
    __shared__ int   sm1[128];
    __shared__ int   sm2[512];

    if (tid < 128) sm1[tid] = m1g[b * 512 + rt * 128 + tid];
    sm2[tid]       = m2g[b * 512 + tid];
    sm2[tid + 256] = m2g[b * 512 + tid + 256];

    // ---- staging addresses (global_load_lds: HW dest = wave-uniform base + lane*16B)
    const int gc = (lane & 3) ^ ((lane >> 2) & 3) ^ ((lane >> 4) & 3);
    const int r0 = w * 16 + (lane >> 2);            // row in call 0 (0..63)
    const ushort* gA0 = n1 + (size_t)(b * 512 + rt * 128 + r0) * 512 + gc * 8;
    const ushort* gA1 = gA0 + 64 * 512;
    ushort* lA0 = sA + w * 512;                     // bytes: w*1024 (wave-uniform)
    ushort* lA1 = sA + 2048 + w * 512;
    ushort* lB0 = sB + w * 512;
    ushort* lB1 = sB + 2048 + w * 512;

    // ---- fragment LDS pointers
    const int sln = (ln & 3) ^ ((ln >> 2) & 3);
    const ushort* aptr[4];
    const ushort* bptr[4];
    #pragma unroll
    for (int mt = 0; mt < 4; ++mt)
        aptr[mt] = &sA[(wm * 64 + mt * 16 + ln) * 32 + ((q ^ sln) << 3)];
    #pragma unroll
    for (int nt = 0; nt < 4; ++nt)
        bptr[nt] = &sB[(wn * 64 + nt * 16 + ln) * 32 + ((q ^ sln) << 3)];

    float runrow = NEGBIG;

    for (int nc = 0; nc < 2; ++nc) {
        const int nb = ct * 256 + nc * 128;
        const ushort* gB0 = n2 + (size_t)(b * 512 + nb + r0) * 512 + gc * 8;
        const ushort* gB1 = gB0 + 64 * 512;

        f32x4 acc[4][4];
        #pragma unroll
        for (int i = 0; i < 4; ++i)
            #pragma unroll
            for (int j = 0; j < 4; ++j)
                acc[i][j] = (f32x4){0.f, 0.f, 0.f, 0.f};

        for (int k0 = 0; k0 < 512; k0 += 32) {
            __syncthreads();   // prev readers done
            __builtin_amdgcn_global_load_lds(CAST_G(gA0 + k0), CAST_LDS(lA0), 16, 0, 0);
            __builtin_amdgcn_global_load_lds(CAST_G(gA1 + k0), CAST_LDS(lA1), 16, 0, 0);
            __builtin_amdgcn_global_load_lds(CAST_G(gB0 + k0), CAST_LDS(lB0), 16, 0, 0);
            __builtin_amdgcn_global_load_lds(CAST_G(gB1 + k0), CAST_LDS(lB1), 16, 0, 0);
            __syncthreads();   // tiles ready

            bf16x8 af[4], bfr[4];
            #pragma unroll
            for (int mt = 0; mt < 4; ++mt)
                af[mt] = *reinterpret_cast<const bf16x8*>(aptr[mt]);
            #pragma unroll
            for (int nt = 0; nt < 4; ++nt)
                bfr[nt] = *reinterpret_cast<const bf16x8*>(bptr[nt]);
            #pragma unroll
            for (int mt = 0; mt < 4; ++mt)
                #pragma unroll
                for (int nt = 0; nt < 4; ++nt)
                    acc[mt][nt] = __builtin_amdgcn_mfma_f32_16x16x32_bf16(
                        af[mt], bfr[nt], acc[mt][nt], 0, 0, 0);
        }

        // ---- epilogue: C/D layout col = ln, row = q*4 + reg (m89/m91)
        #pragma unroll
        for (int mt = 0; mt < 4; ++mt) {
            #pragma unroll
            for (int rg = 0; rg < 4; ++rg) {
                float rm = NEGBIG;
                #pragma unroll
                for (int nt = 0; nt < 4; ++nt) {
                    int j = nb + wn * 64 + nt * 16 + ln;
                    float s = sm2[j] ? acc[mt][nt][rg] : NEGBIG;
                    rm = fmaxf(rm, s);
                }
                rm = fmaxf(rm, __shfl_xor(rm, 1));
                rm = fmaxf(rm, __shfl_xor(rm, 2));
                rm = fmaxf(rm, __shfl_xor(rm, 4));
                rm = fmaxf(rm, __shfl_xor(rm, 8));
                if (ln == 0) spr[wn][wm * 64 + mt * 16 + q * 4 + rg] = rm;
            }
        }
        #pragma unroll
        for (int nt = 0; nt < 4; ++nt) {
            float cm = NEGBIG;
            #pragma unroll
            for (int mt = 0; mt < 4; ++mt)
                #pragma unroll
                for (int rg = 0; rg < 4; ++rg) {
                    int il = wm * 64 + mt * 16 + q * 4 + rg;
                    float s = sm1[il] ? acc[mt][nt][rg] : NEGBIG;
                    cm = fmaxf(cm, s);
                }
            cm = fmaxf(cm, __shfl_xor(cm, 16));
            cm = fmaxf(cm, __shfl_xor(cm, 32));
            if (lane < 16) spc[wm][wn * 64 + nt * 16 + ln] = cm;
        }
        __syncthreads();
        if (tid < 128) {
            runrow = fmaxf(runrow, fmaxf(spr[0][tid], spr[1][tid]));
            colmax_p[((size_t)b * 4 + rt) * 512 + nb + tid] =
                fmaxf(spc[0][tid], spc[1][tid]);
        }
        __syncthreads();
    }
    if (tid < 128)
        rowmax_p[((size_t)b * 2 + ct) * 512 + rt * 128 + tid] = runrow;
}

// ---------------- kernel 3: per-batch final reduction ----------------
__global__ __launch_bounds__(256)
void final_kernel(const int* __restrict__ m1g, const int* __restrict__ m2g,
                  const float* __restrict__ rowmax_p, const float* __restrict__ colmax_p,
                  float* __restrict__ out)
{
    const int b = blockIdx.x;
    const int tid = threadIdx.x;
    const int lane = tid & 63;
    const int w = tid >> 6;

    float sum = 0.f;
    float nn  = 0.f;
    for (int j = tid; j < 512; j += 256) {
        int mm1 = m1g[b * 512 + j];
        int mm2 = m2g[b * 512 + j];
        nn += (float)(mm1 + mm2);
        float rm = fmaxf(rowmax_p[(size_t)b * 1024 + j],
                         rowmax_p[(size_t)b * 1024 + 512 + j]);
        if (mm1) sum += rm;
        const float* cp = colmax_p + (size_t)b * 2048 + j;
        float cm = fmaxf(fmaxf(cp[0], cp[512]), fmaxf(cp[1024], cp[1536]));
        if (mm2) sum += cm;
    }
    #pragma unroll
    for (int m = 32; m; m >>= 1) {
        sum += __shfl_xor(sum, m);
        nn  += __shfl_xor(nn, m);
    }
    __shared__ float ssum[4], snn[4];
    if (lane == 0) { ssum[w] = sum; snn[w] = nn; }
    __syncthreads();
    if (tid == 0) {
        float S = ssum[0] + ssum[1] + ssum[2] + ssum[3];
        float N = snn[0] + snn[1] + snn[2] + snn[3];
        out[b] = S / N;
    }
}

// ================= fallback path (round-1, proven) =================
__global__ __launch_bounds__(256)
void norm_kernel(const float* __restrict__ e1, const float* __restrict__ e2,
                 float* __restrict__ inv1, float* __restrict__ inv2)
{
    const int lane = threadIdx.x & 63;
    const int w    = threadIdx.x >> 6;
    const int row  = blockIdx.x * 4 + w;
    const float* src = (row < 32768) ? (e1 + (size_t)row * 512)
                                     : (e2 + (size_t)(row - 32768) * 512);
    const float4* s4 = reinterpret_cast<const float4*>(src);
    float4 a = s4[lane];
    float4 c = s4[lane + 64];
    float ss = a.x*a.x + a.y*a.y + a.z*a.z + a.w*a.w
             + c.x*c.x + c.y*c.y + c.z*c.z + c.w*c.w;
    #pragma unroll
    for (int m = 32; m; m >>= 1) ss += __shfl_xor(ss, m);
    if (lane == 0) {
        float iv = 1.0f / fmaxf(sqrtf(ss), 1e-8f);
        if (row < 32768) inv1[row] = iv; else inv2[row - 32768] = iv;
    }
}

__global__ __launch_bounds__(256, 2)
void sim_kernel_f32(const float* __restrict__ e1, const float* __restrict__ e2,
                    const int* __restrict__ m1g, const int* __restrict__ m2g,
                    const float* __restrict__ inv1, const float* __restrict__ inv2,
                    float* __restrict__ rowmax_p, float* __restrict__ colmax_p)
{
    const int rt  = blockIdx.x;
    const int ct  = blockIdx.y;
    const int b   = blockIdx.z;
    const int tid = threadIdx.x;
    const int lane = tid & 63;
    const int w    = tid >> 6;
    const int wm   = w >> 1;
    const int wn   = w & 1;
    const int q    = lane >> 4;
    const int ln   = lane & 15;

    __shared__ __align__(16) short sA[128 * 40];
    __shared__ __align__(16) short sB[128 * 40];
    __shared__ float spr[2][128];
    __shared__ float spc[2][128];
    __shared__ int   sm1[128];
    __shared__ int   sm2[512];

    if (tid < 128) sm1[tid] = m1g[b * 512 + rt * 128 + tid];
    sm2[tid]       = m2g[b * 512 + tid];
    sm2[tid + 256] = m2g[b * 512 + tid + 256];

    const int rA = tid >> 1;
    const int h  = tid & 1;
    const size_t baseA = ((size_t)(b * 512 + rt * 128 + rA)) * 512 + h * 16;
    const float iA = inv1[b * 512 + rt * 128 + rA];

    float runrow = NEGBIG;

    for (int nc = 0; nc < 2; ++nc) {
        const int nb = ct * 256 + nc * 128;
        const size_t baseB = ((size_t)(b * 512 + nb + rA)) * 512 + h * 16;
        const float iB = inv2[b * 512 + nb + rA];

        f32x4 acc[4][4];
        #pragma unroll
        for (int i = 0; i < 4; ++i)
            #pragma unroll
            for (int j = 0; j < 4; ++j)
                acc[i][j] = (f32x4){0.f, 0.f, 0.f, 0.f};

        for (int k0 = 0; k0 < 512; k0 += 32) {
            __syncthreads();
            {
                const float4* s4 = reinterpret_cast<const float4*>(e1 + baseA + k0);
                float4 v0 = s4[0], v1 = s4[1], v2 = s4[2], v3 = s4[3];
                uint4 p;
                p.x = packbf(v0.x * iA, v0.y * iA);
                p.y = packbf(v0.z * iA, v0.w * iA);
                p.z = packbf(v1.x * iA, v1.y * iA);
                p.w = packbf(v1.z * iA, v1.w * iA);
                *reinterpret_cast<uint4*>(&sA[rA * 40 + h * 16]) = p;
                p.x = packbf(v2.x * iA, v2.y * iA);
                p.y = packbf(v2.z * iA, v2.w * iA);
                p.z = packbf(v3.x * iA, v3.y * iA);
                p.w = packbf(v3.z * iA, v3.w * iA);
                *reinterpret_cast<uint4*>(&sA[rA * 40 + h * 16 + 8]) = p;
            }
            {
                const float4* s4 = reinterpret_cast<const float4*>(e2 + baseB + k0);
                float4 v0 = s4[0], v1 = s4[1], v2 = s4[2], v3 = s4[3];
                uint4 p;
                p.x = packbf(v0.x * iB, v0.y * iB);
                p.y = packbf(v0.z * iB, v0.w * iB);
                p.z = packbf(v1.x * iB, v1.y * iB);
                p.w = packbf(v1.z * iB, v1.w * iB);
                *reinterpret_cast<uint4*>(&sB[rA * 40 + h * 16]) = p;
                p.x = packbf(v2.x * iB, v2.y * iB);
                p.y = packbf(v2.z * iB, v2.w * iB);
                p.z = packbf(v3.x * iB, v3.y * iB);
                p.w = packbf(v3.z * iB, v3.w * iB);
                *reinterpret_cast<uint4*>(&sB[rA * 40 + h * 16 + 8]) = p;
            }
            __syncthreads();
            bf16x8 af[4], bfr[4];
            #pragma unroll
            for (int mt = 0; mt < 4; ++mt)
                af[mt] = *reinterpret_cast<const bf16x8*>(&sA[(wm * 64 + mt * 16 + ln) * 40 + q * 8]);
            #pragma unroll
            for (int nt = 0; nt < 4; ++nt)
                bfr[nt] = *reinterpret_cast<const bf16x8*>(&sB[(wn * 64 + nt * 16 + ln) * 40 + q * 8]);
            #pragma unroll
            for (int mt = 0; mt < 4; ++mt)
                #pragma unroll
                for (int nt = 0; nt < 4; ++nt)
                    acc[mt][nt] = __builtin_amdgcn_mfma_f32_16x16x32_bf16(
                        af[mt], bfr[nt], acc[mt][nt], 0, 0, 0);
        }

        #pragma unroll
        for (int mt = 0; mt < 4; ++mt) {
            #pragma unroll
            for (int rg = 0; rg < 4; ++rg) {
                float rm = NEGBIG;
                #pragma unroll
                for (int nt = 0; nt < 4; ++nt) {
                    int j = nb + wn * 64 + nt * 16 + ln;
                    float s = sm2[j] ? acc[mt][nt][rg] : NEGBIG;
                    rm = fmaxf(rm, s);
                }
                rm = fmaxf(rm, __shfl_xor(rm, 1));
                rm = fmaxf(rm, __shfl_xor(rm, 2));
                rm = fmaxf(rm, __shfl_xor(rm, 4));
                rm = fmaxf(rm, __shfl_xor(rm, 8));
                if (ln == 0) spr[wn][wm * 64 + mt * 16 + q * 4 + rg] = rm;
            }
        }
        #pragma unroll
        for (int nt = 0; nt < 4; ++nt) {
            float cm = NEGBIG;
            #pragma unroll
            for (int mt = 0; mt < 4; ++mt)
                #pragma unroll
                for (int rg = 0; rg < 4; ++rg) {
                    int il = wm * 64 + mt * 16 + q * 4 + rg;
                    float s = sm1[il] ? acc[mt][nt][rg] : NEGBIG;
                    cm = fmaxf(cm, s);
                }
            cm = fmaxf(cm, __shfl_xor(cm, 16));
            cm = fmaxf(cm, __shfl_xor(cm, 32));
            if (lane < 16) spc[wm][wn * 64 + nt * 16 + ln] = cm;
        }
        __syncthreads();
        if (tid < 128) {
            runrow = fmaxf(runrow, fmaxf(spr[0][tid], spr[1][tid]));
            colmax_p[((size_t)b * 4 + rt) * 512 + nb + tid] =
                fmaxf(spc[0][tid], spc[1][tid]);
        }
        __syncthreads();
    }
    if (tid < 128)
        rowmax_p[((size_t)b * 2 + ct) * 512 + rt * 128 + tid] = runrow;
}

extern "C" void kernel_launch(void* const* d_in, const int* in_sizes, int n_in,
                              void* d_out, int out_size, void* d_ws, size_t ws_size,
                              hipStream_t stream) {
    const float* e1 = (const float*)d_in[0];
    const float* e2 = (const float*)d_in[1];
    const int*   m1 = (const int*)d_in[2];
    const int*   m2 = (const int*)d_in[3];
    float* out = (float*)d_out;

    const size_t NELEM = (size_t)64 * 512 * 512;          // 16,777,216
    const size_t need  = 2 * NELEM * sizeof(ushort)       // n1, n2 (64 MB)
                       + (65536 + 131072) * sizeof(float);

    if (ws_size >= need) {
        ushort* n1 = (ushort*)d_ws;
        ushort* n2 = n1 + NELEM;
        float* tail     = (float*)(n2 + NELEM);
        float* rowmax_p = tail;              // 64*2*512
        float* colmax_p = tail + 65536;      // 64*4*512
        prep_kernel<<<4096, 256, 0, stream>>>(e1, e2, n1, n2);
        sim_kernel<<<dim3(4, 2, 64), 256, 0, stream>>>(n1, n2, m1, m2,
                                                       rowmax_p, colmax_p);
        final_kernel<<<64, 256, 0, stream>>>(m1, m2, rowmax_p, colmax_p, out);
    } else {
        float* ws = (float*)d_ws;
        float* inv1     = ws;
        float* inv2     = ws + 32768;
        float* rowmax_p = ws + 65536;
        float* colmax_p = ws + 131072;
        norm_kernel<<<16384, 256, 0, stream>>>(e1, e2, inv1, inv2);
        sim_kernel_f32<<<dim3(4, 2, 64), 256, 0, stream>>>(e1, e2, m1, m2, inv1, inv2,
                                                           rowmax_p, colmax_p);
        final_kernel<<<64, 256, 0, stream>>>(m1, m2, rowmax_p, colmax_p, out);
    }
}

// Round 4
// 195.732 us; speedup vs baseline: 1.0281x; 1.0281x over previous
//
#include <hip/hip_runtime.h>
#include <hip/hip_bf16.h>

// Problem: B=64, S=512, D=512.
// out[b] = (sum_{valid i} max_{valid j} sim[i,j] + sum_{valid j} max_{valid i} sim[i,j]) / (n1+n2)
// sim = normalize(e1) @ normalize(e2)^T per batch.
//
// Fast path (needs ~65 MB ws):
//   prep_kernel : fp32 -> UNNORMALIZED bf16 (store decoupled from reduction)
//                 + inv L2 norm per row -> ws. Scaling is folded into sim's
//                 epilogue (max commutes with positive scaling), so prep's
//                 critical path is load->pack->store only.
//   sim_kernel  : bf16 MFMA 128x256/block, global_load_lds x16B staging,
//                 XOR-swizzled LDS; acc scaled by inv_i*inv_j in epilogue,
//                 then masked row/col max partials -> ws
//   final_kernel: per-batch reduction -> out
// Fallback path (small ws): round-1 proven kernels.

typedef __attribute__((ext_vector_type(8))) short bf16x8;   // 8 bf16 in 4 VGPRs
typedef __attribute__((ext_vector_type(4))) float f32x4;

#define NEGBIG (-1e9f)
#define CAST_LDS(p) ((__attribute__((address_space(3))) void*)(p))
#define CAST_G(p)   ((const __attribute__((address_space(1))) void*)(p))

__device__ __forceinline__ unsigned bfbits(float f) {
    union { float f; unsigned u; } c; c.f = f;
    // round-to-nearest-even bf16 (inputs finite)
    return (c.u + 0x7fffu + ((c.u >> 16) & 1u)) >> 16;
}
__device__ __forceinline__ unsigned packbf(float lo, float hi) {
    return (bfbits(hi) << 16) | bfbits(lo);
}

// ---------------- fast path kernel 1: cast + norms ----------------
// one wave per row. Store path (load->pack->store) has NO dependence on the
// cross-lane reduction; the norm is a side computation (r3 post-mortem:
// multi-row ILP failed on register residency; r2 1-row chain was serialized
// by the pack's dependence on iv — removed here).
__global__ __launch_bounds__(256)
void prep_kernel(const float* __restrict__ e1, const float* __restrict__ e2,
                 ushort* __restrict__ n1, ushort* __restrict__ n2,
                 float* __restrict__ inv1, float* __restrict__ inv2)
{
    const int lane = threadIdx.x & 63;
    const int w    = threadIdx.x >> 6;
    const int row  = blockIdx.x * 4 + w;          // 0..65535
    const bool is1 = row < 32768;
    const int  r   = is1 ? row : row - 32768;
    const float* src = (is1 ? e1 : e2) + (size_t)r * 512;
    ushort*      dst = (is1 ? n1 : n2) + (size_t)r * 512;

    const float4* s4 = reinterpret_cast<const float4*>(src);
    float4 a = s4[lane * 2];
    float4 c = s4[lane * 2 + 1];

    // store unnormalized bf16 immediately (independent of reduction)
    uint4 p;
    p.x = packbf(a.x, a.y);
    p.y = packbf(a.z, a.w);
    p.z = packbf(c.x, c.y);
    p.w = packbf(c.z, c.w);
    reinterpret_cast<uint4*>(dst)[lane] = p;

    // side computation: inverse L2 norm (fp32, matches reference eps)
    float ss = a.x*a.x + a.y*a.y + a.z*a.z + a.w*a.w
             + c.x*c.x + c.y*c.y + c.z*c.z + c.w*c.w;
    #pragma unroll
    for (int m = 32; m; m >>= 1) ss += __shfl_xor(ss, m);
    if (lane == 0) {
        float iv = 1.0f / fmaxf(sqrtf(ss), 1e-8f);
        (is1 ? inv1 : inv2)[r] = iv;
    }
}

// ---------------- fast path kernel 2: masked sim max partials ----------------
// grid: (rt=0..3, ct=0..1, b=0..63). 256 thr = 4 waves (2x2 of 64x64).
// Tiles: 128 rows x 32 bf16 (64B/row), NO pad (global_load_lds constraint).
// Swizzle: LDS[row][slot] = G[row][slot ^ s(row)], s(r) = (r ^ (r>>2)) & 3
// -> fragment b128 reads land <=2-way on banks.
// Epilogue: acc *= inv_i*inv_j (positive scales commute with max), then masks.
__global__ __launch_bounds__(256, 2)
void sim_kernel(const ushort* __restrict__ n1, const ushort* __restrict__ n2,
                const int* __restrict__ m1g, const int* __restrict__ m2g,
                const float* __restrict__ inv1, const float* __restrict__ inv2,
                float* __restrict__ rowmax_p,   // [B][2][512]
                float* __restrict__ colmax_p)   // [B][4][512]
{
    const int rt  = blockIdx.x;
    const int ct  = blockIdx.y;
    const int b   = blockIdx.z;
    const int tid = threadIdx.x;
    const int lane = tid & 63;
    const int w    = tid >> 6;
    const int wm   = w >> 1;
    const int wn   = w & 1;
    const int q    = lane >> 4;
    const int ln   = lane & 15;

    __shared__ __align__(16) ushort sA[128 * 32];   // 8 KB
    __shared__ __align__(16) ushort sB[128 * 32];   // 8 KB
    __shared__ float spr[2][128];
    __shared__ float spc[2][128];
    __shared__ int   sm1[128];
    __shared__ int   sm2[512];
    __shared__ float sinv1[128];
    __shared__ float sinv2[512];

    if (tid < 128) {
        sm1[tid]   = m1g[b * 512 + rt * 128 + tid];
        sinv1[tid] = inv1[b * 512 + rt * 128 + tid];
    }
    sm2[tid]         = m2g[b * 512 + tid];
    sm2[tid + 256]   = m2g[b * 512 + tid + 256];
    sinv2[tid]       = inv2[b * 512 + tid];
    sinv2[tid + 256] = inv2[b * 512 + tid + 256];

    // ---- staging addresses (global_load_lds: HW dest = wave-uniform base + lane*16B)
    const int gc = (lane & 3) ^ ((lane >> 2) & 3) ^ ((lane >> 4) & 3);
    const int r0 = w * 16 + (lane >> 2);            // row in call 0 (0..63)
    const ushort* gA0 = n1 + (size_t)(b * 512 + rt * 128 + r0) * 512 + gc * 8;
    const ushort* gA1 = gA0 + 64 * 512;
    ushort* lA0 = sA + w * 512;                     // bytes: w*1024 (wave-uniform)
    ushort* lA1 = sA + 2048 + w * 512;
    ushort* lB0 = sB + w * 512;
    ushort* lB1 = sB + 2048 + w * 512;

    // ---- fragment LDS pointers
    const int sln = (ln & 3) ^ ((ln >> 2) & 3);
    const ushort* aptr[4];
    const ushort* bptr[4];
    #pragma unroll
    for (int mt = 0; mt < 4; ++mt)
        aptr[mt] = &sA[(wm * 64 + mt * 16 + ln) * 32 + ((q ^ sln) << 3)];
    #pragma unroll
    for (int nt = 0; nt < 4; ++nt)
        bptr[nt] = &sB[(wn * 64 + nt * 16 + ln) * 32 + ((q ^ sln) << 3)];

    float runrow = NEGBIG;

    for (int nc = 0; nc < 2; ++nc) {
        const int nb = ct * 256 + nc * 128;
        const ushort* gB0 = n2 + (size_t)(b * 512 + nb + r0) * 512 + gc * 8;
        const ushort* gB1 = gB0 + 64 * 512;

        f32x4 acc[4][4];
        #pragma unroll
        for (int i = 0; i < 4; ++i)
            #pragma unroll
            for (int j = 0; j < 4; ++j)
                acc[i][j] = (f32x4){0.f, 0.f, 0.f, 0.f};

        for (int k0 = 0; k0 < 512; k0 += 32) {
            __syncthreads();   // prev readers done
            __builtin_amdgcn_global_load_lds(CAST_G(gA0 + k0), CAST_LDS(lA0), 16, 0, 0);
            __builtin_amdgcn_global_load_lds(CAST_G(gA1 + k0), CAST_LDS(lA1), 16, 0, 0);
            __builtin_amdgcn_global_load_lds(CAST_G(gB0 + k0), CAST_LDS(lB0), 16, 0, 0);
            __builtin_amdgcn_global_load_lds(CAST_G(gB1 + k0), CAST_LDS(lB1), 16, 0, 0);
            __syncthreads();   // tiles ready

            bf16x8 af[4], bfr[4];
            #pragma unroll
            for (int mt = 0; mt < 4; ++mt)
                af[mt] = *reinterpret_cast<const bf16x8*>(aptr[mt]);
            #pragma unroll
            for (int nt = 0; nt < 4; ++nt)
                bfr[nt] = *reinterpret_cast<const bf16x8*>(bptr[nt]);
            #pragma unroll
            for (int mt = 0; mt < 4; ++mt)
                #pragma unroll
                for (int nt = 0; nt < 4; ++nt)
                    acc[mt][nt] = __builtin_amdgcn_mfma_f32_16x16x32_bf16(
                        af[mt], bfr[nt], acc[mt][nt], 0, 0, 0);
        }

        // ---- scale: sim = acc * inv_i * inv_j (C/D layout: col=ln, row=q*4+reg)
        float invj[4];
        f32x4 invi[4];
        #pragma unroll
        for (int nt = 0; nt < 4; ++nt)
            invj[nt] = sinv2[nb + wn * 64 + nt * 16 + ln];
        #pragma unroll
        for (int mt = 0; mt < 4; ++mt)
            #pragma unroll
            for (int rg = 0; rg < 4; ++rg)
                invi[mt][rg] = sinv1[wm * 64 + mt * 16 + q * 4 + rg];
        #pragma unroll
        for (int mt = 0; mt < 4; ++mt)
            #pragma unroll
            for (int nt = 0; nt < 4; ++nt)
                acc[mt][nt] = acc[mt][nt] * (invi[mt] * invj[nt]);

        // ---- masked row maxes
        #pragma unroll
        for (int mt = 0; mt < 4; ++mt) {
            #pragma unroll
            for (int rg = 0; rg < 4; ++rg) {
                float rm = NEGBIG;
                #pragma unroll
                for (int nt = 0; nt < 4; ++nt) {
                    int j = nb + wn * 64 + nt * 16 + ln;
                    float s = sm2[j] ? acc[mt][nt][rg] : NEGBIG;
                    rm = fmaxf(rm, s);
                }
                rm = fmaxf(rm, __shfl_xor(rm, 1));
                rm = fmaxf(rm, __shfl_xor(rm, 2));
                rm = fmaxf(rm, __shfl_xor(rm, 4));
                rm = fmaxf(rm, __shfl_xor(rm, 8));
                if (ln == 0) spr[wn][wm * 64 + mt * 16 + q * 4 + rg] = rm;
            }
        }
        // ---- masked col maxes
        #pragma unroll
        for (int nt = 0; nt < 4; ++nt) {
            float cm = NEGBIG;
            #pragma unroll
            for (int mt = 0; mt < 4; ++mt)
                #pragma unroll
                for (int rg = 0; rg < 4; ++rg) {
                    int il = wm * 64 + mt * 16 + q * 4 + rg;
                    float s = sm1[il] ? acc[mt][nt][rg] : NEGBIG;
                    cm = fmaxf(cm, s);
                }
            cm = fmaxf(cm, __shfl_xor(cm, 16));
            cm = fmaxf(cm, __shfl_xor(cm, 32));
            if (lane < 16) spc[wm][wn * 64 + nt * 16 + ln] = cm;
        }
        __syncthreads();
        if (tid < 128) {
            runrow = fmaxf(runrow, fmaxf(spr[0][tid], spr[1][tid]));
            colmax_p[((size_t)b * 4 + rt) * 512 + nb + tid] =
                fmaxf(spc[0][tid], spc[1][tid]);
        }
        __syncthreads();
    }
    if (tid < 128)
        rowmax_p[((size_t)b * 2 + ct) * 512 + rt * 128 + tid] = runrow;
}

// ---------------- kernel 3: per-batch final reduction ----------------
__global__ __launch_bounds__(256)
void final_kernel(const int* __restrict__ m1g, const int* __restrict__ m2g,
                  const float* __restrict__ rowmax_p, const float* __restrict__ colmax_p,
                  float* __restrict__ out)
{
    const int b = blockIdx.x;
    const int tid = threadIdx.x;
    const int lane = tid & 63;
    const int w = tid >> 6;

    float sum = 0.f;
    float nn  = 0.f;
    for (int j = tid; j < 512; j += 256) {
        int mm1 = m1g[b * 512 + j];
        int mm2 = m2g[b * 512 + j];
        nn += (float)(mm1 + mm2);
        float rm = fmaxf(rowmax_p[(size_t)b * 1024 + j],
                         rowmax_p[(size_t)b * 1024 + 512 + j]);
        if (mm1) sum += rm;
        const float* cp = colmax_p + (size_t)b * 2048 + j;
        float cm = fmaxf(fmaxf(cp[0], cp[512]), fmaxf(cp[1024], cp[1536]));
        if (mm2) sum += cm;
    }
    #pragma unroll
    for (int m = 32; m; m >>= 1) {
        sum += __shfl_xor(sum, m);
        nn  += __shfl_xor(nn, m);
    }
    __shared__ float ssum[4], snn[4];
    if (lane == 0) { ssum[w] = sum; snn[w] = nn; }
    __syncthreads();
    if (tid == 0) {
        float S = ssum[0] + ssum[1] + ssum[2] + ssum[3];
        float N = snn[0] + snn[1] + snn[2] + snn[3];
        out[b] = S / N;
    }
}

// ================= fallback path (round-1, proven) =================
__global__ __launch_bounds__(256)
void norm_kernel(const float* __restrict__ e1, const float* __restrict__ e2,
                 float* __restrict__ inv1, float* __restrict__ inv2)
{
    const int lane = threadIdx.x & 63;
    const int w    = threadIdx.x >> 6;
    const int row  = blockIdx.x * 4 + w;
    const float* src = (row < 32768) ? (e1 + (size_t)row * 512)
                                     : (e2 + (size_t)(row - 32768) * 512);
    const float4* s4 = reinterpret_cast<const float4*>(src);
    float4 a = s4[lane];
    float4 c = s4[lane + 64];
    float ss = a.x*a.x + a.y*a.y + a.z*a.z + a.w*a.w
             + c.x*c.x + c.y*c.y + c.z*c.z + c.w*c.w;
    #pragma unroll
    for (int m = 32; m; m >>= 1) ss += __shfl_xor(ss, m);
    if (lane == 0) {
        float iv = 1.0f / fmaxf(sqrtf(ss), 1e-8f);
        if (row < 32768) inv1[row] = iv; else inv2[row - 32768] = iv;
    }
}

__global__ __launch_bounds__(256, 2)
void sim_kernel_f32(const float* __restrict__ e1, const float* __restrict__ e2,
                    const int* __restrict__ m1g, const int* __restrict__ m2g,
                    const float* __restrict__ inv1, const float* __restrict__ inv2,
                    float* __restrict__ rowmax_p, float* __restrict__ colmax_p)
{
    const int rt  = blockIdx.x;
    const int ct  = blockIdx.y;
    const int b   = blockIdx.z;
    const int tid = threadIdx.x;
    const int lane = tid & 63;
    const int w    = tid >> 6;
    const int wm   = w >> 1;
    const int wn   = w & 1;
    const int q    = lane >> 4;
    const int ln   = lane & 15;

    __shared__ __align__(16) short sA[128 * 40];
    __shared__ __align__(16) short sB[128 * 40];
    __shared__ float spr[2][128];
    __shared__ float spc[2][128];
    __shared__ int   sm1[128];
    __shared__ int   sm2[512];

    if (tid < 128) sm1[tid] = m1g[b * 512 + rt * 128 + tid];
    sm2[tid]       = m2g[b * 512 + tid];
    sm2[tid + 256] = m2g[b * 512 + tid + 256];

    const int rA = tid >> 1;
    const int h  = tid & 1;
    const size_t baseA = ((size_t)(b * 512 + rt * 128 + rA)) * 512 + h * 16;
    const float iA = inv1[b * 512 + rt * 128 + rA];

    float runrow = NEGBIG;

    for (int nc = 0; nc < 2; ++nc) {
        const int nb = ct * 256 + nc * 128;
        const size_t baseB = ((size_t)(b * 512 + nb + rA)) * 512 + h * 16;
        const float iB = inv2[b * 512 + nb + rA];

        f32x4 acc[4][4];
        #pragma unroll
        for (int i = 0; i < 4; ++i)
            #pragma unroll
            for (int j = 0; j < 4; ++j)
                acc[i][j] = (f32x4){0.f, 0.f, 0.f, 0.f};

        for (int k0 = 0; k0 < 512; k0 += 32) {
            __syncthreads();
            {
                const float4* s4 = reinterpret_cast<const float4*>(e1 + baseA + k0);
                float4 v0 = s4[0], v1 = s4[1], v2 = s4[2], v3 = s4[3];
                uint4 p;
                p.x = packbf(v0.x * iA, v0.y * iA);
                p.y = packbf(v0.z * iA, v0.w * iA);
                p.z = packbf(v1.x * iA, v1.y * iA);
                p.w = packbf(v1.z * iA, v1.w * iA);
                *reinterpret_cast<uint4*>(&sA[rA * 40 + h * 16]) = p;
                p.x = packbf(v2.x * iA, v2.y * iA);
                p.y = packbf(v2.z * iA, v2.w * iA);
                p.z = packbf(v3.x * iA, v3.y * iA);
                p.w = packbf(v3.z * iA, v3.w * iA);
                *reinterpret_cast<uint4*>(&sA[rA * 40 + h * 16 + 8]) = p;
            }
            {
                const float4* s4 = reinterpret_cast<const float4*>(e2 + baseB + k0);
                float4 v0 = s4[0], v1 = s4[1], v2 = s4[2], v3 = s4[3];
                uint4 p;
                p.x = packbf(v0.x * iB, v0.y * iB);
                p.y = packbf(v0.z * iB, v0.w * iB);
                p.z = packbf(v1.x * iB, v1.y * iB);
                p.w = packbf(v1.z * iB, v1.w * iB);
                *reinterpret_cast<uint4*>(&sB[rA * 40 + h * 16]) = p;
                p.x = packbf(v2.x * iB, v2.y * iB);
                p.y = packbf(v2.z * iB, v2.w * iB);
                p.z = packbf(v3.x * iB, v3.y * iB);
                p.w = packbf(v3.z * iB, v3.w * iB);
                *reinterpret_cast<uint4*>(&sB[rA * 40 + h * 16 + 8]) = p;
            }
            __syncthreads();
            bf16x8 af[4], bfr[4];
            #pragma unroll
            for (int mt = 0; mt < 4; ++mt)
                af[mt] = *reinterpret_cast<const bf16x8*>(&sA[(wm * 64 + mt * 16 + ln) * 40 + q * 8]);
            #pragma unroll
            for (int nt = 0; nt < 4; ++nt)
                bfr[nt] = *reinterpret_cast<const bf16x8*>(&sB[(wn * 64 + nt * 16 + ln) * 40 + q * 8]);
            #pragma unroll
            for (int mt = 0; mt < 4; ++mt)
                #pragma unroll
                for (int nt = 0; nt < 4; ++nt)
                    acc[mt][nt] = __builtin_amdgcn_mfma_f32_16x16x32_bf16(
                        af[mt], bfr[nt], acc[mt][nt], 0, 0, 0);
        }

        #pragma unroll
        for (int mt = 0; mt < 4; ++mt) {
            #pragma unroll
            for (int rg = 0; rg < 4; ++rg) {
                float rm = NEGBIG;
                #pragma unroll
                for (int nt = 0; nt < 4; ++nt) {
                    int j = nb + wn * 64 + nt * 16 + ln;
                    float s = sm2[j] ? acc[mt][nt][rg] : NEGBIG;
                    rm = fmaxf(rm, s);
                }
                rm = fmaxf(rm, __shfl_xor(rm, 1));
                rm = fmaxf(rm, __shfl_xor(rm, 2));
                rm = fmaxf(rm, __shfl_xor(rm, 4));
                rm = fmaxf(rm, __shfl_xor(rm, 8));
                if (ln == 0) spr[wn][wm * 64 + mt * 16 + q * 4 + rg] = rm;
            }
        }
        #pragma unroll
        for (int nt = 0; nt < 4; ++nt) {
            float cm = NEGBIG;
            #pragma unroll
            for (int mt = 0; mt < 4; ++mt)
                #pragma unroll
                for (int rg = 0; rg < 4; ++rg) {
                    int il = wm * 64 + mt * 16 + q * 4 + rg;
                    float s = sm1[il] ? acc[mt][nt][rg] : NEGBIG;
                    cm = fmaxf(cm, s);
                }
            cm = fmaxf(cm, __shfl_xor(cm, 16));
            cm = fmaxf(cm, __shfl_xor(cm, 32));
            if (lane < 16) spc[wm][wn * 64 + nt * 16 + ln] = cm;
        }
        __syncthreads();
        if (tid < 128) {
            runrow = fmaxf(runrow, fmaxf(spr[0][tid], spr[1][tid]));
            colmax_p[((size_t)b * 4 + rt) * 512 + nb + tid] =
                fmaxf(spc[0][tid], spc[1][tid]);
        }
        __syncthreads();
    }
    if (tid < 128)
        rowmax_p[((size_t)b * 2 + ct) * 512 + rt * 128 + tid] = runrow;
}

extern "C" void kernel_launch(void* const* d_in, const int* in_sizes, int n_in,
                              void* d_out, int out_size, void* d_ws, size_t ws_size,
                              hipStream_t stream) {
    const float* e1 = (const float*)d_in[0];
    const float* e2 = (const float*)d_in[1];
    const int*   m1 = (const int*)d_in[2];
    const int*   m2 = (const int*)d_in[3];
    float* out = (float*)d_out;

    const size_t NELEM = (size_t)64 * 512 * 512;          // 16,777,216
    const size_t need  = 2 * NELEM * sizeof(ushort)       // n1, n2 (64 MB)
                       + (32768 + 32768 + 65536 + 131072) * sizeof(float);

    if (ws_size >= need) {
        ushort* n1 = (ushort*)d_ws;
        ushort* n2 = n1 + NELEM;
        float* tail     = (float*)(n2 + NELEM);
        float* inv1     = tail;              // 32768
        float* inv2     = tail + 32768;      // 32768
        float* rowmax_p = tail + 65536;      // 64*2*512
        float* colmax_p = tail + 131072;     // 64*4*512
        prep_kernel<<<16384, 256, 0, stream>>>(e1, e2, n1, n2, inv1, inv2);
        sim_kernel<<<dim3(4, 2, 64), 256, 0, stream>>>(n1, n2, m1, m2, inv1, inv2,
                                                       rowmax_p, colmax_p);
        final_kernel<<<64, 256, 0, stream>>>(m1, m2, rowmax_p, colmax_p, out);
    } else {
        float* ws = (float*)d_ws;
        float* inv1     = ws;
        float* inv2     = ws + 32768;
        float* rowmax_p = ws + 65536;
        float* colmax_p = ws + 131072;
        norm_kernel<<<16384, 256, 0, stream>>>(e1, e2, inv1, inv2);
        sim_kernel_f32<<<dim3(4, 2, 64), 256, 0, stream>>>(e1, e2, m1, m2, inv1, inv2,
                                                           rowmax_p, colmax_p);
        final_kernel<<<64, 256, 0, stream>>>(m1, m2, rowmax_p, colmax_p, out);
    }
}